// Round 12
// baseline (232.055 us; speedup 1.0000x reference)
//
#include <hip/hip_runtime.h>
#include <cstdint>
#include <cstddef>
#include <math.h>

// Problem constants: N=2, L=S=2048, Hd=512, H=8, E=64, TOPK=32
#define NH     8
#define EH     64
#define HD     512
#define NBATCH 2
#define LSEQ   2048
#define TK     32

// ws layout: q f32 [0, 2097152) | k f32 row-major [2097152, 4194304) |
//            v f32 [4194304, 6291456) | khi bf16-frag u16 at ws+6291456 (4 MiB)
// khi: per head 128 key-tiles x 2 ksteps x 64 lanes x 8 u16 (= 131072 u16/head).
// out layout (f32): V[2][2048][512] then A[2][8][2048][2048]

using f32x4  = __attribute__((ext_vector_type(4))) float;
using bf16x8 = __attribute__((ext_vector_type(8))) short;
using u16x8  = __attribute__((ext_vector_type(8))) unsigned short;
using u16x4  = __attribute__((ext_vector_type(4))) unsigned short;

__device__ __forceinline__ unsigned short f2b(float f) {   // f32 -> bf16 RNE bits
    unsigned u = __float_as_uint(f);
    return (unsigned short)((u + 0x7FFFu + ((u >> 16) & 1u)) >> 16);
}
__device__ __forceinline__ unsigned f2key(float f) {       // order-preserving u32
    unsigned u = __float_as_uint(f);
    return (u & 0x80000000u) ? ~u : (u | 0x80000000u);
}
__device__ __forceinline__ float key2f(unsigned k) {
    return __uint_as_float((k & 0x80000000u) ? (k ^ 0x80000000u) : ~k);
}
__device__ __forceinline__ unsigned umax2(unsigned a, unsigned b) { return a > b ? a : b; }
__device__ __forceinline__ int swzA(int r, int c) { return c ^ ((r >> 2) & 7); }
__device__ __forceinline__ int swzB(int r, int c) { return c ^ (((r >> 2) ^ (r >> 5)) & 7); }

// ---------------------------------------------------------------------------
// Kernel 1: fused projections out = X @ W^T + b (row-major head-major);
// 64x128 tile, 4x8 micro-tile. z==1 also emits khi (bf16, MFMA B-frag order).
// kst ALIASES Xs/Ws (dead after k-loop) -> LDS 42->24.5KB -> 4 blocks/CU.
// Grid (64, 4, 3), 256 threads.  (round-11 version, kept)
// ---------------------------------------------------------------------------
__global__ __launch_bounds__(256, 4) void proj_kernel(
    const float* __restrict__ Xq, const float* __restrict__ Xk, const float* __restrict__ Xv,
    const float* __restrict__ Wq, const float* __restrict__ Bq,
    const float* __restrict__ Wk, const float* __restrict__ Bk,
    const float* __restrict__ Wv, const float* __restrict__ Bv,
    float* __restrict__ ws)
{
    const int z = blockIdx.z;
    const float* X = (z == 0) ? Xq : (z == 1) ? Xk : Xv;
    const float* W = (z == 0) ? Wq : (z == 1) ? Wk : Wv;
    const float* B = (z == 0) ? Bq : (z == 1) ? Bk : Bv;
    float* out = ws + (size_t)z * 2097152;
    unsigned short* khi = (unsigned short*)(ws + 6291456);

    // 24576 B: Xs (8KB) + Ws (16KB) during k-loop; kst (17408B) aliases both
    // in the epilogue (Xs/Ws are dead after the final __syncthreads).
    __shared__ char smem[24576];
    float4* Xs = (float4*)smem;                 // [64*8]
    float4* Ws = (float4*)(smem + 8192);        // [128*8]
    unsigned short* kst = (unsigned short*)smem; // [64*136] (epilogue only)

    const int tid = threadIdx.x;
    const int tx = tid & 15, ty = tid >> 4;     // 16x16 threads, micro 4 rows x 8 cols
    const int m0 = blockIdx.x * 64, n0 = blockIdx.y * 128;

    float acc[4][8];
    #pragma unroll
    for (int i = 0; i < 4; ++i)
        #pragma unroll
        for (int j = 0; j < 8; ++j) acc[i][j] = 0.f;

    for (int k0 = 0; k0 < HD; k0 += 32) {
        #pragma unroll
        for (int it = 0; it < 2; ++it) {        // X: 512 float4
            int f = tid + it * 256;
            int row = f >> 3, c = f & 7;
            Xs[row * 8 + swzA(row, c)] = *(const float4*)&X[(size_t)(m0 + row) * HD + k0 + c * 4];
        }
        #pragma unroll
        for (int it = 0; it < 4; ++it) {        // W: 1024 float4
            int f = tid + it * 256;
            int row = f >> 3, c = f & 7;
            Ws[row * 8 + swzB(row, c)] = *(const float4*)&W[(size_t)(n0 + row) * HD + k0 + c * 4];
        }
        __syncthreads();
        #pragma unroll
        for (int c = 0; c < 8; ++c) {
            float4 av[4], bv[8];
            #pragma unroll
            for (int i = 0; i < 4; ++i) { int r = ty * 4 + i; av[i] = Xs[r * 8 + swzA(r, c)]; }
            #pragma unroll
            for (int j = 0; j < 8; ++j) { int r = tx * 8 + j; bv[j] = Ws[r * 8 + swzB(r, c)]; }
            #pragma unroll
            for (int i = 0; i < 4; ++i)
                #pragma unroll
                for (int j = 0; j < 8; ++j) {
                    acc[i][j] = fmaf(av[i].x, bv[j].x, acc[i][j]);
                    acc[i][j] = fmaf(av[i].y, bv[j].y, acc[i][j]);
                    acc[i][j] = fmaf(av[i].z, bv[j].z, acc[i][j]);
                    acc[i][j] = fmaf(av[i].w, bv[j].w, acc[i][j]);
                }
        }
        __syncthreads();   // after this (final iter) Xs/Ws are dead -> kst may alias
    }

    // epilogue: bias + vectorized stores (+ kst bf16 restage for z==1)
    float4 bb[2];
    bb[0] = *(const float4*)&B[n0 + tx * 8 + 0];
    bb[1] = *(const float4*)&B[n0 + tx * 8 + 4];
    #pragma unroll
    for (int i = 0; i < 4; ++i) {
        int m = m0 + ty * 4 + i;
        int n = m >> 11, s = m & 2047;
        #pragma unroll
        for (int jj = 0; jj < 2; ++jj) {
            int o0 = n0 + tx * 8 + jj * 4;
            int head = n * NH + (o0 >> 6), e0 = o0 & 63;
            float4 val;
            val.x = acc[i][jj * 4 + 0] + bb[jj].x;
            val.y = acc[i][jj * 4 + 1] + bb[jj].y;
            val.z = acc[i][jj * 4 + 2] + bb[jj].z;
            val.w = acc[i][jj * 4 + 3] + bb[jj].w;
            *(float4*)&out[(size_t)head * 131072 + (size_t)s * EH + e0] = val;
            if (z == 1) {
                u16x4 b4;
                b4[0] = f2b(val.x); b4[1] = f2b(val.y);
                b4[2] = f2b(val.z); b4[3] = f2b(val.w);
                *(u16x4*)&kst[(ty * 4 + i) * 136 + tx * 8 + jj * 4] = b4;
            }
        }
    }

    if (z == 1) {
        __syncthreads();
        const int base_head = (m0 >> 11) * NH + (n0 >> 6);   // first of 2 heads in tile
        const int kt0 = (m0 & 2047) >> 4;
        #pragma unroll
        for (int it = 0; it < 4; ++it) {
            int g = tid + it * 256;                 // 1024 frags: 2 heads x 4 kt x 2 ks x 64 lanes
            int lane_g = g & 63;
            int rest = g >> 6;                      // 0..15
            int head_loc = rest >> 3, ksb = (rest >> 2) & 1, kt = rest & 3;
            int s_loc = kt * 16 + (lane_g & 15);
            int ecol = head_loc * 64 + ksb * 32 + ((lane_g >> 4) << 3);
            u16x8 vv = *(const u16x8*)&kst[s_loc * 136 + ecol];
            size_t idx = ((((size_t)(base_head + head_loc) * 128 + (kt0 + kt)) * 2 + ksb) * 64 + lane_g) * 8;
            *(u16x8*)&khi[idx] = vv;
        }
    }
}

// ---------------------------------------------------------------------------
// Kernel 2: MFMA bf16 approx QK^T -> tau-margin candidates -> exact f32
// rescore -> exact top-32 -> softmax -> A, V.
// Round-12: PLAIN stores for A and V (nt-stores reverted — L2 write-back
// absorbs the 270MB A stream; nt serialized it toward HBM, −7us regression).
// Selection math identical to rounds 9-11.
// ---------------------------------------------------------------------------
__device__ __forceinline__ unsigned long long sort64_desc(unsigned long long v, int lane) {
    #pragma unroll
    for (int k = 2; k <= 64; k <<= 1)
        #pragma unroll
        for (int j = k >> 1; j >= 1; j >>= 1) {
            unsigned long long o = __shfl_xor(v, j, 64);
            bool up = ((lane & k) != 0);                 // descending
            bool keepmin = (((lane & j) == 0) == up);
            unsigned long long lo = v < o ? v : o;
            unsigned long long hi = v > o ? v : o;
            v = keepmin ? lo : hi;
        }
    return v;
}
__device__ __forceinline__ unsigned sort32_desc(unsigned v, int lane) {
    #pragma unroll
    for (int k = 2; k <= 64; k <<= 1)
        #pragma unroll
        for (int j = k >> 1; j >= 1; j >>= 1) {
            unsigned o = __shfl_xor(v, j, 64);
            bool up = ((lane & k) != 0);                 // descending
            bool keepmin = (((lane & j) == 0) == up);
            unsigned lo = v < o ? v : o, hi = v > o ? v : o;
            v = keepmin ? lo : hi;
        }
    return v;
}
__device__ __forceinline__ unsigned long long merge_top64(unsigned long long a, unsigned long long b, int lane) {
    unsigned long long br = __shfl(b, 63 - lane, 64);
    unsigned long long m = a > br ? a : br;
    #pragma unroll
    for (int j = 32; j >= 1; j >>= 1) {
        unsigned long long o = __shfl_xor(m, j, 64);
        bool keepmax = ((lane & j) == 0);
        unsigned long long mx = m > o ? m : o;
        unsigned long long mn = m < o ? m : o;
        m = keepmax ? mx : mn;
    }
    return m;
}

__global__ __launch_bounds__(512, 4) void attn_kernel(
    const float* __restrict__ ws, float* __restrict__ outV, float* __restrict__ outA)
{
    const float* qw = ws;
    const float* kw = ws + 2097152;
    const float* vw = ws + 4194304;
    const unsigned short* khi = (const unsigned short*)(ws + 6291456);

    __shared__ unsigned short scores16[2048 * 16];   // 65536 B, [key][row^(key&12)]
    __shared__ float qs[EH * 16];                    // 4096 B, [e][row]
    __shared__ unsigned short candArr[8 * 2 * 192];  // 6144 B, per (wave,row)

    const int tid  = threadIdx.x;
    const int lane = tid & 63;
    const int uwv  = __builtin_amdgcn_readfirstlane(tid) >> 6;  // wave id (SGPR)

    // XCD swizzle: 2048 blocks, 256/XCD = 2 heads per XCD (working set ~3.5MB in L2)
    unsigned bid = blockIdx.x;
    unsigned id  = (bid & 7u) * 256u + (bid >> 3);
    const int head = (int)(id >> 7);           // n*8+h
    const int l0   = (int)(id & 127u) * 16;
    const size_t headoff = (size_t)head * 131072;

    // stage q: qs[e][row], rows l0..l0+15
    #pragma unroll
    for (int it = 0; it < 2; ++it) {
        int i = tid + it * 512;
        int row = i & 15, e = i >> 4;
        qs[i] = qw[headoff + (size_t)(l0 + row) * EH + e];
    }
    __syncthreads();

    // ---- Phase A: MFMA approx scores -> u16 keys in LDS (b64 frag stores) ----
    {
        bf16x8 afrag[2];
        #pragma unroll
        for (int ks = 0; ks < 2; ++ks)
            #pragma unroll
            for (int j = 0; j < 8; ++j) {
                int e = ks * 32 + ((lane >> 4) << 3) + j;
                afrag[ks][j] = (short)f2b(qs[e * 16 + (lane & 15)]);
            }

        #pragma unroll
        for (int kt = 0; kt < 16; ++kt) {
            f32x4 acc = (f32x4)(0.f);
            int ktg = uwv * 16 + kt;
            #pragma unroll
            for (int ks = 0; ks < 2; ++ks) {
                bf16x8 b = *(const bf16x8*)(khi + (size_t)head * 131072 +
                              ((((size_t)ktg * 2 + ks) * 64 + lane) << 3));
                acc = __builtin_amdgcn_mfma_f32_16x16x32_bf16(afrag[ks], b, acc, 0, 0, 0);
            }
            int key = uwv * 256 + kt * 16 + (lane & 15);
            int rbase = (lane >> 4) << 2;          // C: col=lane&15, row=rbase+reg
            int p = rbase ^ (key & 12);            // bank-spread swizzle
            u16x4 s4;
            #pragma unroll
            for (int reg = 0; reg < 4; ++reg)
                s4[reg] = (unsigned short)(f2key(acc[reg]) >> 16);
            *(u16x4*)&scores16[key * 16 + p] = s4;   // one aligned b64 store
        }
    }
    __syncthreads();

    // ---- Select: wave uwv owns rows 2uwv, 2uwv+1; fully wave-local ----
    const unsigned long long lmlt = (1ull << lane) - 1ull;
    int selS[2]; float selW[2];

    // read both rows' keys once: u32 = {row r0, row r0+1} u16 pair
    const int r0 = 2 * uwv;
    unsigned pk[32];
    #pragma unroll
    for (int t = 0; t < 32; ++t) {
        int key = t * 64 + lane;
        int p0 = r0 ^ (key & 12);                  // even; pair-adjacent with r0+1
        pk[t] = *(const unsigned*)&scores16[key * 16 + p0];
    }
    __syncthreads();   // all pk reads done before any wave scribbles abuf below

    #pragma unroll
    for (int rr2 = 0; rr2 < 2; ++rr2) {
        const int lrow = l0 + r0 + rr2;
        unsigned short* cand = candArr + (uwv * 2 + rr2) * 192;

        // 1. per-lane max over this row's 32 keys
        unsigned mx = 0;
        #pragma unroll
        for (int t = 0; t < 32; ++t) {
            unsigned a = rr2 ? (pk[t] >> 16) : (pk[t] & 0xFFFFu);
            mx = umax2(mx, a);
        }
        // 2. bitonic ascending sort of lane maxima; tau16 = rank-32 (lane 32)
        {
            unsigned v = mx;
            #pragma unroll
            for (int k = 2; k <= 64; k <<= 1)
                #pragma unroll
                for (int j = k >> 1; j >= 1; j >>= 1) {
                    unsigned o = __shfl_xor(v, j);
                    bool up = ((lane & k) == 0);
                    bool keepmin = (((lane & j) == 0) == up);
                    unsigned lo = v < o ? v : o, hi = v > o ? v : o;
                    v = keepmin ? lo : hi;
                }
            mx = __shfl(v, 32);
        }
        const unsigned tau16 = mx;
        const float tauf = key2f(tau16 << 16);
        const unsigned thr16 = f2key(tauf - 0.35f) >> 16;   // margin: bf16+trunc error

        // 3. ballot-prefix compaction (ascending global index order)
        int Nc = 0;
        #pragma unroll
        for (int t = 0; t < 32; ++t) {
            unsigned a = rr2 ? (pk[t] >> 16) : (pk[t] & 0xFFFFu);
            bool c = a >= thr16;
            unsigned long long b = __ballot(c);
            if (c) {
                int p = Nc + __popcll(b & lmlt);
                if (p < 192) cand[p] = (unsigned short)(t * 64 + lane);
            }
            Nc += __popcll(b);
        }
        if (Nc > 192) Nc = 192;

        // 4. q row via wave-uniform global loads (scalar broadcast)
        const float* qrow = qw + headoff + (size_t)lrow * EH;
        float4 qv[16];
        #pragma unroll
        for (int c4 = 0; c4 < 16; ++c4) qv[c4] = *(const float4*)&qrow[c4 * 4];

        if (Nc <= 64) {
            // ---- fast path: one chunk, u32 sort + ballot tie-break ----
            bool valid = lane < Nc;
            int si = valid ? (int)cand[lane] : 0;
            const float* krow = kw + headoff + (size_t)si * EH;
            float sc = 0.f;
            #pragma unroll
            for (int c4 = 0; c4 < 16; ++c4) {      // ascending e: bit-identical
                float4 kv = *(const float4*)&krow[c4 * 4];
                sc = fmaf(qv[c4].x, kv.x, sc);
                sc = fmaf(qv[c4].y, kv.y, sc);
                sc = fmaf(qv[c4].z, kv.z, sc);
                sc = fmaf(qv[c4].w, kv.w, sc);
            }
            unsigned k32 = valid ? f2key(sc) : 0u;   // 0 < any real key
            unsigned sorted = sort32_desc(k32, lane);
            const unsigned T   = __builtin_amdgcn_readlane((int)sorted, 31);
            const unsigned M32 = __builtin_amdgcn_readlane((int)sorted, 0);
            unsigned long long bgt = __ballot(k32 > T);
            int needEq = TK - __popcll(bgt);
            unsigned long long beq = __ballot(valid && (k32 == T));
            int eqrank = __popcll(beq & lmlt);       // cand ascending-index => lowest idx first
            bool kept = valid && ((k32 > T) || ((k32 == T) && (eqrank < needEq)));
            const float M = key2f(M32);
            float ee = kept ? __expf(0.125f * (sc - M)) : 0.f;
            float Z = ee;
            #pragma unroll
            for (int d = 1; d < 64; d <<= 1) Z += __shfl_xor(Z, d);
            float w = ee / Z;
            // compact (si, w) to lanes 0..31 via ds_permute push (rank = kept prefix)
            unsigned long long bk = __ballot(kept);
            int rk = __popcll(bk & lmlt);
            int addr = kept ? (rk * 4) : 252;        // non-kept push to dead lane 63
            int psi = __builtin_amdgcn_ds_permute(addr, si);
            int pw  = __builtin_amdgcn_ds_permute(addr, __float_as_int(w));
            selS[rr2] = psi;
            selW[rr2] = __int_as_float(pw);
        } else {
            // ---- fallback: u64 composite chunked sort (rounds 5-9 proven) ----
            const int nch = (Nc + 63) >> 6;
            unsigned long long best = 0ull;
            for (int c = 0; c < nch; ++c) {
                int p = c * 64 + lane;
                bool valid = p < Nc;
                int si = valid ? (int)cand[p] : 0;
                const float* krow = kw + headoff + (size_t)si * EH;
                float sc = 0.f;
                #pragma unroll
                for (int c4 = 0; c4 < 16; ++c4) {
                    float4 kv = *(const float4*)&krow[c4 * 4];
                    sc = fmaf(qv[c4].x, kv.x, sc);
                    sc = fmaf(qv[c4].y, kv.y, sc);
                    sc = fmaf(qv[c4].z, kv.z, sc);
                    sc = fmaf(qv[c4].w, kv.w, sc);
                }
                unsigned long long comp = valid
                    ? ((((unsigned long long)f2key(sc)) << 32) | (unsigned)(~si))
                    : 0ull;
                comp = sort64_desc(comp, lane);
                best = (c == 0) ? comp : merge_top64(best, comp, lane);
            }
            unsigned key32 = (unsigned)(best >> 32);
            int si = (int)(~((unsigned)best)) & 2047;
            float sc = key2f(key32);
            float M = __shfl(sc, 0);
            float ee = (lane < TK) ? __expf(0.125f * (sc - M)) : 0.f;
            float Z = ee;
            #pragma unroll
            for (int d = 1; d < 64; d <<= 1) Z += __shfl_xor(Z, d);
            selS[rr2] = si;
            selW[rr2] = ee / Z;
        }
    }

    // ---- Epilogue: A rows staged in wave-private 8KB LDS + V rows ----
    float* abuf = (float*)((char*)scores16 + uwv * 8192);   // wave-private 2048 f32
    {
        float4* ab4 = (float4*)abuf;
        const float4 z4 = make_float4(0.f, 0.f, 0.f, 0.f);
        #pragma unroll
        for (int u = 0; u < 8; ++u) ab4[u * 64 + lane] = z4;   // zero ONCE per wave
    }
    #pragma unroll
    for (int rr2 = 0; rr2 < 2; ++rr2) {
        const int lrow = l0 + r0 + rr2;
        float4* ab4 = (float4*)abuf;
        if (lane < TK) abuf[selS[rr2]] = selW[rr2];          // wave-local scatter
        float* Arow = outA + ((size_t)head * 2048 + lrow) * 2048;
        #pragma unroll
        for (int u = 0; u < 8; ++u)
            *(float4*)&Arow[(u * 64 + lane) * 4] = ab4[u * 64 + lane];
        if (lane < TK) abuf[selS[rr2]] = 0.f;                // clear only scatters

        // V: broadcast slots via readlane (VALU) -> coalesced loads
        float acc = 0.f;
        int   siv = selS[rr2];
        unsigned wbits = __float_as_uint(selW[rr2]);
        #pragma unroll
        for (int i = 0; i < TK; ++i) {
            int s_i   = __builtin_amdgcn_readlane(siv, i);
            float w_i = __uint_as_float((unsigned)__builtin_amdgcn_readlane((int)wbits, i));
            acc = fmaf(w_i, vw[headoff + (size_t)s_i * EH + lane], acc);
        }
        const int n = head >> 3, h = head & 7;
        outV[((size_t)(n * 2048 + lrow)) * 512 + h * 64 + lane] = acc;
    }
}

// ---------------------------------------------------------------------------
extern "C" void kernel_launch(void* const* d_in, const int* in_sizes, int n_in,
                              void* d_out, int out_size, void* d_ws, size_t ws_size,
                              hipStream_t stream)
{
    (void)in_sizes; (void)n_in; (void)out_size; (void)ws_size;
    const float* q  = (const float*)d_in[0];
    const float* k  = (const float*)d_in[1];
    const float* v  = (const float*)d_in[2];
    const float* Wq = (const float*)d_in[3];
    const float* bq = (const float*)d_in[4];
    const float* Wk = (const float*)d_in[5];
    const float* bk = (const float*)d_in[6];
    const float* Wv = (const float*)d_in[7];
    const float* bv = (const float*)d_in[8];
    float* ws   = (float*)d_ws;  // 28 MiB
    float* outV = (float*)d_out;
    float* outA = outV + (size_t)NBATCH * LSEQ * HD;

    proj_kernel<<<dim3(64, 4, 3), 256, 0, stream>>>(q, k, v, Wq, bq, Wk, bk, Wv, bv, ws);
    attn_kernel<<<dim3(2048, 1, 1), 512, 0, stream>>>(ws, outV, outA);
}

// Round 13
// 231.649 us; speedup vs baseline: 1.0018x; 1.0018x over previous
//
#include <hip/hip_runtime.h>
#include <cstdint>
#include <cstddef>
#include <math.h>

// Problem constants: N=2, L=S=2048, Hd=512, H=8, E=64, TOPK=32
#define NH     8
#define EH     64
#define HD     512
#define NBATCH 2
#define LSEQ   2048
#define TK     32

// ws layout: q f32 [0, 2097152) | k f32 row-major [2097152, 4194304) |
//            v f32 [4194304, 6291456) | khi bf16-frag u16 at ws+6291456 (4 MiB)
// khi: per head 128 key-tiles x 2 ksteps x 64 lanes x 8 u16 (= 131072 u16/head).
// out layout (f32): V[2][2048][512] then A[2][8][2048][2048]

using f32x4  = __attribute__((ext_vector_type(4))) float;
using bf16x8 = __attribute__((ext_vector_type(8))) short;
using u16x8  = __attribute__((ext_vector_type(8))) unsigned short;
using u16x4  = __attribute__((ext_vector_type(4))) unsigned short;

__device__ __forceinline__ unsigned short f2b(float f) {   // f32 -> bf16 RNE bits
    unsigned u = __float_as_uint(f);
    return (unsigned short)((u + 0x7FFFu + ((u >> 16) & 1u)) >> 16);
}
__device__ __forceinline__ unsigned f2key(float f) {       // order-preserving u32
    unsigned u = __float_as_uint(f);
    return (u & 0x80000000u) ? ~u : (u | 0x80000000u);
}
__device__ __forceinline__ float key2f(unsigned k) {
    return __uint_as_float((k & 0x80000000u) ? (k ^ 0x80000000u) : ~k);
}
__device__ __forceinline__ unsigned umax2(unsigned a, unsigned b) { return a > b ? a : b; }
__device__ __forceinline__ int swzA(int r, int c) { return c ^ ((r >> 2) & 7); }
__device__ __forceinline__ int swzB(int r, int c) { return c ^ (((r >> 2) ^ (r >> 5)) & 7); }

// ---------------------------------------------------------------------------
// Kernel 1: fused projections out = X @ W^T + b (row-major head-major);
// 64x128 tile, 4x8 micro-tile. z==1 also emits khi (bf16, MFMA B-frag order).
// ROUND-8 VERSION (separate kst LDS, launch_bounds(256,3)) — the proj-union
// (256,4) variant of rounds 11-12 regressed ~12us from VGPR pressure.
// Grid (64, 4, 3), 256 threads.
// ---------------------------------------------------------------------------
__global__ __launch_bounds__(256, 3) void proj_kernel(
    const float* __restrict__ Xq, const float* __restrict__ Xk, const float* __restrict__ Xv,
    const float* __restrict__ Wq, const float* __restrict__ Bq,
    const float* __restrict__ Wk, const float* __restrict__ Bk,
    const float* __restrict__ Wv, const float* __restrict__ Bv,
    float* __restrict__ ws)
{
    const int z = blockIdx.z;
    const float* X = (z == 0) ? Xq : (z == 1) ? Xk : Xv;
    const float* W = (z == 0) ? Wq : (z == 1) ? Wk : Wv;
    const float* B = (z == 0) ? Bq : (z == 1) ? Bk : Bv;
    float* out = ws + (size_t)z * 2097152;
    unsigned short* khi = (unsigned short*)(ws + 6291456);

    __shared__ float4 Xs[64 * 8];               // 8 KB
    __shared__ float4 Ws[128 * 8];              // 16 KB
    __shared__ unsigned short kst[64 * 136];    // 17408 B (z==1 restage)

    const int tid = threadIdx.x;
    const int tx = tid & 15, ty = tid >> 4;     // 16x16 threads, micro 4 rows x 8 cols
    const int m0 = blockIdx.x * 64, n0 = blockIdx.y * 128;

    float acc[4][8];
    #pragma unroll
    for (int i = 0; i < 4; ++i)
        #pragma unroll
        for (int j = 0; j < 8; ++j) acc[i][j] = 0.f;

    for (int k0 = 0; k0 < HD; k0 += 32) {
        #pragma unroll
        for (int it = 0; it < 2; ++it) {        // X: 512 float4
            int f = tid + it * 256;
            int row = f >> 3, c = f & 7;
            Xs[row * 8 + swzA(row, c)] = *(const float4*)&X[(size_t)(m0 + row) * HD + k0 + c * 4];
        }
        #pragma unroll
        for (int it = 0; it < 4; ++it) {        // W: 1024 float4
            int f = tid + it * 256;
            int row = f >> 3, c = f & 7;
            Ws[row * 8 + swzB(row, c)] = *(const float4*)&W[(size_t)(n0 + row) * HD + k0 + c * 4];
        }
        __syncthreads();
        #pragma unroll
        for (int c = 0; c < 8; ++c) {
            float4 av[4], bv[8];
            #pragma unroll
            for (int i = 0; i < 4; ++i) { int r = ty * 4 + i; av[i] = Xs[r * 8 + swzA(r, c)]; }
            #pragma unroll
            for (int j = 0; j < 8; ++j) { int r = tx * 8 + j; bv[j] = Ws[r * 8 + swzB(r, c)]; }
            #pragma unroll
            for (int i = 0; i < 4; ++i)
                #pragma unroll
                for (int j = 0; j < 8; ++j) {
                    acc[i][j] = fmaf(av[i].x, bv[j].x, acc[i][j]);
                    acc[i][j] = fmaf(av[i].y, bv[j].y, acc[i][j]);
                    acc[i][j] = fmaf(av[i].z, bv[j].z, acc[i][j]);
                    acc[i][j] = fmaf(av[i].w, bv[j].w, acc[i][j]);
                }
        }
        __syncthreads();
    }

    // epilogue: bias + vectorized stores (+ kst bf16 restage for z==1)
    float4 bb[2];
    bb[0] = *(const float4*)&B[n0 + tx * 8 + 0];
    bb[1] = *(const float4*)&B[n0 + tx * 8 + 4];
    #pragma unroll
    for (int i = 0; i < 4; ++i) {
        int m = m0 + ty * 4 + i;
        int n = m >> 11, s = m & 2047;
        #pragma unroll
        for (int jj = 0; jj < 2; ++jj) {
            int o0 = n0 + tx * 8 + jj * 4;
            int head = n * NH + (o0 >> 6), e0 = o0 & 63;
            float4 val;
            val.x = acc[i][jj * 4 + 0] + bb[jj].x;
            val.y = acc[i][jj * 4 + 1] + bb[jj].y;
            val.z = acc[i][jj * 4 + 2] + bb[jj].z;
            val.w = acc[i][jj * 4 + 3] + bb[jj].w;
            *(float4*)&out[(size_t)head * 131072 + (size_t)s * EH + e0] = val;
            if (z == 1) {
                u16x4 b4;
                b4[0] = f2b(val.x); b4[1] = f2b(val.y);
                b4[2] = f2b(val.z); b4[3] = f2b(val.w);
                *(u16x4*)&kst[(ty * 4 + i) * 136 + tx * 8 + jj * 4] = b4;
            }
        }
    }

    if (z == 1) {
        __syncthreads();
        const int base_head = (m0 >> 11) * NH + (n0 >> 6);   // first of 2 heads in tile
        const int kt0 = (m0 & 2047) >> 4;
        #pragma unroll
        for (int it = 0; it < 4; ++it) {
            int g = tid + it * 256;                 // 1024 frags: 2 heads x 4 kt x 2 ks x 64 lanes
            int lane_g = g & 63;
            int rest = g >> 6;                      // 0..15
            int head_loc = rest >> 3, ksb = (rest >> 2) & 1, kt = rest & 3;
            int s_loc = kt * 16 + (lane_g & 15);
            int ecol = head_loc * 64 + ksb * 32 + ((lane_g >> 4) << 3);
            u16x8 vv = *(const u16x8*)&kst[s_loc * 136 + ecol];
            size_t idx = ((((size_t)(base_head + head_loc) * 128 + (kt0 + kt)) * 2 + ksb) * 64 + lane_g) * 8;
            *(u16x8*)&khi[idx] = vv;
        }
    }
}

// ---------------------------------------------------------------------------
// Kernel 2: MFMA bf16 approx QK^T -> tau-margin candidates -> exact f32
// rescore -> exact top-32 -> softmax -> A, V.
// Round-13: 1024-thread blocks (16 waves), one select-row per wave ->
// 32 waves/CU (2x occupancy, same 76KB LDS). A-epilogue in two barrier-phased
// halves sharing 8x8KB staging. Selection math bit-identical to round 9.
// ---------------------------------------------------------------------------
__device__ __forceinline__ unsigned long long sort64_desc(unsigned long long v, int lane) {
    #pragma unroll
    for (int k = 2; k <= 64; k <<= 1)
        #pragma unroll
        for (int j = k >> 1; j >= 1; j >>= 1) {
            unsigned long long o = __shfl_xor(v, j, 64);
            bool up = ((lane & k) != 0);                 // descending
            bool keepmin = (((lane & j) == 0) == up);
            unsigned long long lo = v < o ? v : o;
            unsigned long long hi = v > o ? v : o;
            v = keepmin ? lo : hi;
        }
    return v;
}
__device__ __forceinline__ unsigned sort32_desc(unsigned v, int lane) {
    #pragma unroll
    for (int k = 2; k <= 64; k <<= 1)
        #pragma unroll
        for (int j = k >> 1; j >= 1; j >>= 1) {
            unsigned o = __shfl_xor(v, j, 64);
            bool up = ((lane & k) != 0);                 // descending
            bool keepmin = (((lane & j) == 0) == up);
            unsigned lo = v < o ? v : o, hi = v > o ? v : o;
            v = keepmin ? lo : hi;
        }
    return v;
}
__device__ __forceinline__ unsigned long long merge_top64(unsigned long long a, unsigned long long b, int lane) {
    unsigned long long br = __shfl(b, 63 - lane, 64);
    unsigned long long m = a > br ? a : br;
    #pragma unroll
    for (int j = 32; j >= 1; j >>= 1) {
        unsigned long long o = __shfl_xor(m, j, 64);
        bool keepmax = ((lane & j) == 0);
        unsigned long long mx = m > o ? m : o;
        unsigned long long mn = m < o ? m : o;
        m = keepmax ? mx : mn;
    }
    return m;
}

__global__ __launch_bounds__(1024, 8) void attn_kernel(
    const float* __restrict__ ws, float* __restrict__ outV, float* __restrict__ outA)
{
    const float* qw = ws;
    const float* kw = ws + 2097152;
    const float* vw = ws + 4194304;
    const unsigned short* khi = (const unsigned short*)(ws + 6291456);

    __shared__ unsigned short scores16[2048 * 16];   // 65536 B, [key][row^(key&12)]
    __shared__ float qs[EH * 16];                    // 4096 B, [e][row]
    __shared__ unsigned short candArr[16 * 192];     // 6144 B, per wave

    const int tid  = threadIdx.x;
    const int lane = tid & 63;
    const int uwv  = __builtin_amdgcn_readfirstlane(tid) >> 6;  // wave id 0..15 (SGPR)

    // XCD swizzle: 2048 blocks, 256/XCD = 2 heads per XCD (working set ~3.5MB in L2)
    unsigned bid = blockIdx.x;
    unsigned id  = (bid & 7u) * 256u + (bid >> 3);
    const int head = (int)(id >> 7);           // n*8+h
    const int l0   = (int)(id & 127u) * 16;
    const size_t headoff = (size_t)head * 131072;

    // stage q: qs[e][row], rows l0..l0+15 (1024 elements, one pass)
    {
        int row = tid & 15, e = tid >> 4;
        qs[e * 16 + row] = qw[headoff + (size_t)(l0 + row) * EH + e];
    }
    __syncthreads();

    // ---- Phase A: wave uwv computes key-tiles 8uwv..8uwv+7 ----
    {
        bf16x8 afrag[2];
        #pragma unroll
        for (int ks = 0; ks < 2; ++ks)
            #pragma unroll
            for (int j = 0; j < 8; ++j) {
                int e = ks * 32 + ((lane >> 4) << 3) + j;
                afrag[ks][j] = (short)f2b(qs[e * 16 + (lane & 15)]);
            }

        #pragma unroll
        for (int kt = 0; kt < 8; ++kt) {
            f32x4 acc = (f32x4)(0.f);
            int ktg = uwv * 8 + kt;
            #pragma unroll
            for (int ks = 0; ks < 2; ++ks) {
                bf16x8 b = *(const bf16x8*)(khi + (size_t)head * 131072 +
                              ((((size_t)ktg * 2 + ks) * 64 + lane) << 3));
                acc = __builtin_amdgcn_mfma_f32_16x16x32_bf16(afrag[ks], b, acc, 0, 0, 0);
            }
            int key = ktg * 16 + (lane & 15);
            int rbase = (lane >> 4) << 2;          // C: col=lane&15, row=rbase+reg
            int p = rbase ^ (key & 12);            // bank-spread swizzle
            u16x4 s4;
            #pragma unroll
            for (int reg = 0; reg < 4; ++reg)
                s4[reg] = (unsigned short)(f2key(acc[reg]) >> 16);
            *(u16x4*)&scores16[key * 16 + p] = s4;   // one aligned b64 store
        }
    }
    __syncthreads();

    // ---- Select: wave uwv owns row uwv; fully wave-local ----
    const unsigned long long lmlt = (1ull << lane) - 1ull;
    const int r  = uwv;
    const int pb = r & 14;                     // even pair base in the u32
    const int hi = r & 1;
    int selS; float selW;

    unsigned pk[32];
    #pragma unroll
    for (int t = 0; t < 32; ++t) {
        int key = t * 64 + lane;
        int p0 = pb ^ (key & 12);
        pk[t] = *(const unsigned*)&scores16[key * 16 + p0];
    }
    __syncthreads();   // all pk reads done before any wave scribbles abuf below

    {
        const int lrow = l0 + r;
        unsigned short* cand = candArr + uwv * 192;

        // 1. per-lane max over this row's 32 keys
        unsigned mx = 0;
        #pragma unroll
        for (int t = 0; t < 32; ++t) {
            unsigned a = hi ? (pk[t] >> 16) : (pk[t] & 0xFFFFu);
            mx = umax2(mx, a);
        }
        // 2. bitonic ascending sort of lane maxima; tau16 = rank-32 (lane 32)
        {
            unsigned v = mx;
            #pragma unroll
            for (int k = 2; k <= 64; k <<= 1)
                #pragma unroll
                for (int j = k >> 1; j >= 1; j >>= 1) {
                    unsigned o = __shfl_xor(v, j);
                    bool up = ((lane & k) == 0);
                    bool keepmin = (((lane & j) == 0) == up);
                    unsigned lo = v < o ? v : o, hi2 = v > o ? v : o;
                    v = keepmin ? lo : hi2;
                }
            mx = __shfl(v, 32);
        }
        const unsigned tau16 = mx;
        const float tauf = key2f(tau16 << 16);
        const unsigned thr16 = f2key(tauf - 0.35f) >> 16;   // margin: bf16+trunc error

        // 3. ballot-prefix compaction (ascending global index order)
        int Nc = 0;
        #pragma unroll
        for (int t = 0; t < 32; ++t) {
            unsigned a = hi ? (pk[t] >> 16) : (pk[t] & 0xFFFFu);
            bool c = a >= thr16;
            unsigned long long b = __ballot(c);
            if (c) {
                int p = Nc + __popcll(b & lmlt);
                if (p < 192) cand[p] = (unsigned short)(t * 64 + lane);
            }
            Nc += __popcll(b);
        }
        if (Nc > 192) Nc = 192;

        // 4. q row via wave-uniform global loads (scalar broadcast)
        const float* qrow = qw + headoff + (size_t)lrow * EH;
        float4 qv[16];
        #pragma unroll
        for (int c4 = 0; c4 < 16; ++c4) qv[c4] = *(const float4*)&qrow[c4 * 4];

        if (Nc <= 64) {
            // ---- fast path: one chunk, u32 sort + ballot tie-break ----
            bool valid = lane < Nc;
            int si = valid ? (int)cand[lane] : 0;
            const float* krow = kw + headoff + (size_t)si * EH;
            float sc = 0.f;
            #pragma unroll
            for (int c4 = 0; c4 < 16; ++c4) {      // ascending e: bit-identical
                float4 kv = *(const float4*)&krow[c4 * 4];
                sc = fmaf(qv[c4].x, kv.x, sc);
                sc = fmaf(qv[c4].y, kv.y, sc);
                sc = fmaf(qv[c4].z, kv.z, sc);
                sc = fmaf(qv[c4].w, kv.w, sc);
            }
            unsigned k32 = valid ? f2key(sc) : 0u;   // 0 < any real key
            unsigned sorted = sort32_desc(k32, lane);
            const unsigned T   = __builtin_amdgcn_readlane((int)sorted, 31);
            const unsigned M32 = __builtin_amdgcn_readlane((int)sorted, 0);
            unsigned long long bgt = __ballot(k32 > T);
            int needEq = TK - __popcll(bgt);
            unsigned long long beq = __ballot(valid && (k32 == T));
            int eqrank = __popcll(beq & lmlt);       // cand ascending-index => lowest idx first
            bool kept = valid && ((k32 > T) || ((k32 == T) && (eqrank < needEq)));
            const float M = key2f(M32);
            float ee = kept ? __expf(0.125f * (sc - M)) : 0.f;
            float Z = ee;
            #pragma unroll
            for (int d = 1; d < 64; d <<= 1) Z += __shfl_xor(Z, d);
            float w = ee / Z;
            // compact (si, w) to lanes 0..31 via ds_permute push (rank = kept prefix)
            unsigned long long bk = __ballot(kept);
            int rk = __popcll(bk & lmlt);
            int addr = kept ? (rk * 4) : 252;        // non-kept push to dead lane 63
            int psi = __builtin_amdgcn_ds_permute(addr, si);
            int pw  = __builtin_amdgcn_ds_permute(addr, __float_as_int(w));
            selS = psi;
            selW = __int_as_float(pw);
        } else {
            // ---- fallback: u64 composite chunked sort (rounds 5-12 proven) ----
            const int nch = (Nc + 63) >> 6;
            unsigned long long best = 0ull;
            for (int c = 0; c < nch; ++c) {
                int p = c * 64 + lane;
                bool valid = p < Nc;
                int si = valid ? (int)cand[p] : 0;
                const float* krow = kw + headoff + (size_t)si * EH;
                float sc = 0.f;
                #pragma unroll
                for (int c4 = 0; c4 < 16; ++c4) {
                    float4 kv = *(const float4*)&krow[c4 * 4];
                    sc = fmaf(qv[c4].x, kv.x, sc);
                    sc = fmaf(qv[c4].y, kv.y, sc);
                    sc = fmaf(qv[c4].z, kv.z, sc);
                    sc = fmaf(qv[c4].w, kv.w, sc);
                }
                unsigned long long comp = valid
                    ? ((((unsigned long long)f2key(sc)) << 32) | (unsigned)(~si))
                    : 0ull;
                comp = sort64_desc(comp, lane);
                best = (c == 0) ? comp : merge_top64(best, comp, lane);
            }
            unsigned key32 = (unsigned)(best >> 32);
            int si = (int)(~((unsigned)best)) & 2047;
            float sc = key2f(key32);
            float M = __shfl(sc, 0);
            float ee = (lane < TK) ? __expf(0.125f * (sc - M)) : 0.f;
            float Z = ee;
            #pragma unroll
            for (int d = 1; d < 64; d <<= 1) Z += __shfl_xor(Z, d);
            selS = si;
            selW = ee / Z;
        }
    }

    // ---- Epilogue: A rows in two barrier-phased halves (8x8KB staging) ----
    float* abuf = (float*)((char*)scores16 + (uwv & 7) * 8192);   // 2048 f32
    const int lrow = l0 + r;
    float* Arow = outA + ((size_t)head * 2048 + lrow) * 2048;
    const float4 z4 = make_float4(0.f, 0.f, 0.f, 0.f);

    if (uwv < 8) {
        float4* ab4 = (float4*)abuf;
        #pragma unroll
        for (int u = 0; u < 8; ++u) ab4[u * 64 + lane] = z4;
        if (lane < TK) abuf[selS] = selW;
        #pragma unroll
        for (int u = 0; u < 8; ++u)
            *(float4*)&Arow[(u * 64 + lane) * 4] = ab4[u * 64 + lane];
    }
    __syncthreads();
    if (uwv >= 8) {
        float4* ab4 = (float4*)abuf;
        #pragma unroll
        for (int u = 0; u < 8; ++u) ab4[u * 64 + lane] = z4;
        if (lane < TK) abuf[selS] = selW;
        #pragma unroll
        for (int u = 0; u < 8; ++u)
            *(float4*)&Arow[(u * 64 + lane) * 4] = ab4[u * 64 + lane];
    }

    // V: broadcast slots via readlane (VALU) -> coalesced loads
    {
        float acc = 0.f;
        int   siv = selS;
        unsigned wbits = __float_as_uint(selW);
        #pragma unroll
        for (int i = 0; i < TK; ++i) {
            int s_i   = __builtin_amdgcn_readlane(siv, i);
            float w_i = __uint_as_float((unsigned)__builtin_amdgcn_readlane((int)wbits, i));
            acc = fmaf(w_i, vw[headoff + (size_t)s_i * EH + lane], acc);
        }
        const int n = head >> 3, h = head & 7;
        outV[((size_t)(n * 2048 + lrow)) * 512 + h * 64 + lane] = acc;
    }
}

// ---------------------------------------------------------------------------
extern "C" void kernel_launch(void* const* d_in, const int* in_sizes, int n_in,
                              void* d_out, int out_size, void* d_ws, size_t ws_size,
                              hipStream_t stream)
{
    (void)in_sizes; (void)n_in; (void)out_size; (void)ws_size;
    const float* q  = (const float*)d_in[0];
    const float* k  = (const float*)d_in[1];
    const float* v  = (const float*)d_in[2];
    const float* Wq = (const float*)d_in[3];
    const float* bq = (const float*)d_in[4];
    const float* Wk = (const float*)d_in[5];
    const float* bk = (const float*)d_in[6];
    const float* Wv = (const float*)d_in[7];
    const float* bv = (const float*)d_in[8];
    float* ws   = (float*)d_ws;  // 28 MiB
    float* outV = (float*)d_out;
    float* outA = outV + (size_t)NBATCH * LSEQ * HD;

    proj_kernel<<<dim3(64, 4, 3), 256, 0, stream>>>(q, k, v, Wq, bq, Wk, bk, Wv, bv, ws);
    attn_kernel<<<dim3(2048, 1, 1), 1024, 0, stream>>>(ws, outV, outA);
}

// Round 14
// 217.639 us; speedup vs baseline: 1.0662x; 1.0644x over previous
//
#include <hip/hip_runtime.h>
#include <cstdint>
#include <cstddef>
#include <math.h>

// Problem constants: N=2, L=S=2048, Hd=512, H=8, E=64, TOPK=32
#define NH     8
#define EH     64
#define HD     512
#define NBATCH 2
#define LSEQ   2048
#define TK     32

// ws layout: q f32 [0, 2097152) | k f32 row-major [2097152, 4194304) |
//            v f32 [4194304, 6291456) | khi bf16-frag u16 at ws+6291456 (4 MiB)
// khi: per head 128 key-tiles x 2 ksteps x 64 lanes x 8 u16 (= 131072 u16/head).
// out layout (f32): V[2][2048][512] then A[2][8][2048][2048]

using f32x4  = __attribute__((ext_vector_type(4))) float;
using bf16x8 = __attribute__((ext_vector_type(8))) short;
using u16x8  = __attribute__((ext_vector_type(8))) unsigned short;
using u16x4  = __attribute__((ext_vector_type(4))) unsigned short;

__device__ __forceinline__ unsigned short f2b(float f) {   // f32 -> bf16 RNE bits
    unsigned u = __float_as_uint(f);
    return (unsigned short)((u + 0x7FFFu + ((u >> 16) & 1u)) >> 16);
}
__device__ __forceinline__ unsigned f2key(float f) {       // order-preserving u32
    unsigned u = __float_as_uint(f);
    return (u & 0x80000000u) ? ~u : (u | 0x80000000u);
}
__device__ __forceinline__ float key2f(unsigned k) {
    return __uint_as_float((k & 0x80000000u) ? (k ^ 0x80000000u) : ~k);
}
__device__ __forceinline__ unsigned umax2(unsigned a, unsigned b) { return a > b ? a : b; }
__device__ __forceinline__ int swzA(int r, int c) { return c ^ ((r >> 2) & 7); }
__device__ __forceinline__ int swzB(int r, int c) { return c ^ (((r >> 2) ^ (r >> 5)) & 7); }

// ---------------------------------------------------------------------------
// Kernel 1: fused projections out = X @ W^T + b (row-major head-major);
// 64x128 tile, 4x8 micro-tile. z==1 also emits khi (bf16, MFMA B-frag order).
// R8 version: separate kst LDS, launch_bounds(256,3). Grid (64, 4, 3).
// ---------------------------------------------------------------------------
__global__ __launch_bounds__(256, 3) void proj_kernel(
    const float* __restrict__ Xq, const float* __restrict__ Xk, const float* __restrict__ Xv,
    const float* __restrict__ Wq, const float* __restrict__ Bq,
    const float* __restrict__ Wk, const float* __restrict__ Bk,
    const float* __restrict__ Wv, const float* __restrict__ Bv,
    float* __restrict__ ws)
{
    const int z = blockIdx.z;
    const float* X = (z == 0) ? Xq : (z == 1) ? Xk : Xv;
    const float* W = (z == 0) ? Wq : (z == 1) ? Wk : Wv;
    const float* B = (z == 0) ? Bq : (z == 1) ? Bk : Bv;
    float* out = ws + (size_t)z * 2097152;
    unsigned short* khi = (unsigned short*)(ws + 6291456);

    __shared__ float4 Xs[64 * 8];               // 8 KB
    __shared__ float4 Ws[128 * 8];              // 16 KB
    __shared__ unsigned short kst[64 * 136];    // 17408 B (z==1 restage)

    const int tid = threadIdx.x;
    const int tx = tid & 15, ty = tid >> 4;     // 16x16 threads, micro 4 rows x 8 cols
    const int m0 = blockIdx.x * 64, n0 = blockIdx.y * 128;

    float acc[4][8];
    #pragma unroll
    for (int i = 0; i < 4; ++i)
        #pragma unroll
        for (int j = 0; j < 8; ++j) acc[i][j] = 0.f;

    for (int k0 = 0; k0 < HD; k0 += 32) {
        #pragma unroll
        for (int it = 0; it < 2; ++it) {        // X: 512 float4
            int f = tid + it * 256;
            int row = f >> 3, c = f & 7;
            Xs[row * 8 + swzA(row, c)] = *(const float4*)&X[(size_t)(m0 + row) * HD + k0 + c * 4];
        }
        #pragma unroll
        for (int it = 0; it < 4; ++it) {        // W: 1024 float4
            int f = tid + it * 256;
            int row = f >> 3, c = f & 7;
            Ws[row * 8 + swzB(row, c)] = *(const float4*)&W[(size_t)(n0 + row) * HD + k0 + c * 4];
        }
        __syncthreads();
        #pragma unroll
        for (int c = 0; c < 8; ++c) {
            float4 av[4], bv[8];
            #pragma unroll
            for (int i = 0; i < 4; ++i) { int r = ty * 4 + i; av[i] = Xs[r * 8 + swzA(r, c)]; }
            #pragma unroll
            for (int j = 0; j < 8; ++j) { int r = tx * 8 + j; bv[j] = Ws[r * 8 + swzB(r, c)]; }
            #pragma unroll
            for (int i = 0; i < 4; ++i)
                #pragma unroll
                for (int j = 0; j < 8; ++j) {
                    acc[i][j] = fmaf(av[i].x, bv[j].x, acc[i][j]);
                    acc[i][j] = fmaf(av[i].y, bv[j].y, acc[i][j]);
                    acc[i][j] = fmaf(av[i].z, bv[j].z, acc[i][j]);
                    acc[i][j] = fmaf(av[i].w, bv[j].w, acc[i][j]);
                }
        }
        __syncthreads();
    }

    // epilogue: bias + vectorized stores (+ kst bf16 restage for z==1)
    float4 bb[2];
    bb[0] = *(const float4*)&B[n0 + tx * 8 + 0];
    bb[1] = *(const float4*)&B[n0 + tx * 8 + 4];
    #pragma unroll
    for (int i = 0; i < 4; ++i) {
        int m = m0 + ty * 4 + i;
        int n = m >> 11, s = m & 2047;
        #pragma unroll
        for (int jj = 0; jj < 2; ++jj) {
            int o0 = n0 + tx * 8 + jj * 4;
            int head = n * NH + (o0 >> 6), e0 = o0 & 63;
            float4 val;
            val.x = acc[i][jj * 4 + 0] + bb[jj].x;
            val.y = acc[i][jj * 4 + 1] + bb[jj].y;
            val.z = acc[i][jj * 4 + 2] + bb[jj].z;
            val.w = acc[i][jj * 4 + 3] + bb[jj].w;
            *(float4*)&out[(size_t)head * 131072 + (size_t)s * EH + e0] = val;
            if (z == 1) {
                u16x4 b4;
                b4[0] = f2b(val.x); b4[1] = f2b(val.y);
                b4[2] = f2b(val.z); b4[3] = f2b(val.w);
                *(u16x4*)&kst[(ty * 4 + i) * 136 + tx * 8 + jj * 4] = b4;
            }
        }
    }

    if (z == 1) {
        __syncthreads();
        const int base_head = (m0 >> 11) * NH + (n0 >> 6);   // first of 2 heads in tile
        const int kt0 = (m0 & 2047) >> 4;
        #pragma unroll
        for (int it = 0; it < 4; ++it) {
            int g = tid + it * 256;                 // 1024 frags: 2 heads x 4 kt x 2 ks x 64 lanes
            int lane_g = g & 63;
            int rest = g >> 6;                      // 0..15
            int head_loc = rest >> 3, ksb = (rest >> 2) & 1, kt = rest & 3;
            int s_loc = kt * 16 + (lane_g & 15);
            int ecol = head_loc * 64 + ksb * 32 + ((lane_g >> 4) << 3);
            u16x8 vv = *(const u16x8*)&kst[s_loc * 136 + ecol];
            size_t idx = ((((size_t)(base_head + head_loc) * 128 + (kt0 + kt)) * 2 + ksb) * 64 + lane_g) * 8;
            *(u16x8*)&khi[idx] = vv;
        }
    }
}

// ---------------------------------------------------------------------------
// Kernel 2: MFMA bf16 approx QK^T -> tau-margin candidates -> exact f32
// rescore -> exact top-32 -> softmax -> A, V.
// R9 structure (512 thr, slim select) + NT stores for A/V (R11-vs-R12 A/B
// measured nt = -4.7us: keeps khi/k/v/q resident in the XCD L2).
// ---------------------------------------------------------------------------
__device__ __forceinline__ unsigned long long sort64_desc(unsigned long long v, int lane) {
    #pragma unroll
    for (int k = 2; k <= 64; k <<= 1)
        #pragma unroll
        for (int j = k >> 1; j >= 1; j >>= 1) {
            unsigned long long o = __shfl_xor(v, j, 64);
            bool up = ((lane & k) != 0);                 // descending
            bool keepmin = (((lane & j) == 0) == up);
            unsigned long long lo = v < o ? v : o;
            unsigned long long hi = v > o ? v : o;
            v = keepmin ? lo : hi;
        }
    return v;
}
__device__ __forceinline__ unsigned sort32_desc(unsigned v, int lane) {
    #pragma unroll
    for (int k = 2; k <= 64; k <<= 1)
        #pragma unroll
        for (int j = k >> 1; j >= 1; j >>= 1) {
            unsigned o = __shfl_xor(v, j, 64);
            bool up = ((lane & k) != 0);                 // descending
            bool keepmin = (((lane & j) == 0) == up);
            unsigned lo = v < o ? v : o, hi = v > o ? v : o;
            v = keepmin ? lo : hi;
        }
    return v;
}
__device__ __forceinline__ unsigned long long merge_top64(unsigned long long a, unsigned long long b, int lane) {
    unsigned long long br = __shfl(b, 63 - lane, 64);
    unsigned long long m = a > br ? a : br;
    #pragma unroll
    for (int j = 32; j >= 1; j >>= 1) {
        unsigned long long o = __shfl_xor(m, j, 64);
        bool keepmax = ((lane & j) == 0);
        unsigned long long mx = m > o ? m : o;
        unsigned long long mn = m < o ? m : o;
        m = keepmax ? mx : mn;
    }
    return m;
}

__global__ __launch_bounds__(512, 4) void attn_kernel(
    const float* __restrict__ ws, float* __restrict__ outV, float* __restrict__ outA)
{
    const float* qw = ws;
    const float* kw = ws + 2097152;
    const float* vw = ws + 4194304;
    const unsigned short* khi = (const unsigned short*)(ws + 6291456);

    __shared__ unsigned short scores16[2048 * 16];   // 65536 B, [key][row^(key&12)]
    __shared__ float qs[EH * 16];                    // 4096 B, [e][row]
    __shared__ unsigned short candArr[8 * 2 * 192];  // 6144 B, per (wave,row)

    const int tid  = threadIdx.x;
    const int lane = tid & 63;
    const int uwv  = __builtin_amdgcn_readfirstlane(tid) >> 6;  // wave id (SGPR)

    // XCD swizzle: 2048 blocks, 256/XCD = 2 heads per XCD (working set ~3.5MB in L2)
    unsigned bid = blockIdx.x;
    unsigned id  = (bid & 7u) * 256u + (bid >> 3);
    const int head = (int)(id >> 7);           // n*8+h
    const int l0   = (int)(id & 127u) * 16;
    const size_t headoff = (size_t)head * 131072;

    // stage q: qs[e][row], rows l0..l0+15
    #pragma unroll
    for (int it = 0; it < 2; ++it) {
        int i = tid + it * 512;
        int row = i & 15, e = i >> 4;
        qs[i] = qw[headoff + (size_t)(l0 + row) * EH + e];
    }
    __syncthreads();

    // ---- Phase A: MFMA approx scores -> u16 keys in LDS (b64 frag stores) ----
    {
        bf16x8 afrag[2];
        #pragma unroll
        for (int ks = 0; ks < 2; ++ks)
            #pragma unroll
            for (int j = 0; j < 8; ++j) {
                int e = ks * 32 + ((lane >> 4) << 3) + j;
                afrag[ks][j] = (short)f2b(qs[e * 16 + (lane & 15)]);
            }

        #pragma unroll
        for (int kt = 0; kt < 16; ++kt) {
            f32x4 acc = (f32x4)(0.f);
            int ktg = uwv * 16 + kt;
            #pragma unroll
            for (int ks = 0; ks < 2; ++ks) {
                bf16x8 b = *(const bf16x8*)(khi + (size_t)head * 131072 +
                              ((((size_t)ktg * 2 + ks) * 64 + lane) << 3));
                acc = __builtin_amdgcn_mfma_f32_16x16x32_bf16(afrag[ks], b, acc, 0, 0, 0);
            }
            int key = uwv * 256 + kt * 16 + (lane & 15);
            int rbase = (lane >> 4) << 2;          // C: col=lane&15, row=rbase+reg
            int p = rbase ^ (key & 12);            // bank-spread swizzle
            u16x4 s4;
            #pragma unroll
            for (int reg = 0; reg < 4; ++reg)
                s4[reg] = (unsigned short)(f2key(acc[reg]) >> 16);
            *(u16x4*)&scores16[key * 16 + p] = s4;   // one aligned b64 store
        }
    }
    __syncthreads();

    // ---- Select: wave uwv owns rows 2uwv, 2uwv+1; fully wave-local ----
    const unsigned long long lmlt = (1ull << lane) - 1ull;
    int selS[2]; float selW[2];

    // read both rows' keys once: u32 = {row r0, row r0+1} u16 pair
    const int r0 = 2 * uwv;
    unsigned pk[32];
    #pragma unroll
    for (int t = 0; t < 32; ++t) {
        int key = t * 64 + lane;
        int p0 = r0 ^ (key & 12);                  // even; pair-adjacent with r0+1
        pk[t] = *(const unsigned*)&scores16[key * 16 + p0];
    }
    __syncthreads();   // all pk reads done before any wave scribbles abuf below

    #pragma unroll
    for (int rr2 = 0; rr2 < 2; ++rr2) {
        const int lrow = l0 + r0 + rr2;
        unsigned short* cand = candArr + (uwv * 2 + rr2) * 192;

        // 1. per-lane max over this row's 32 keys
        unsigned mx = 0;
        #pragma unroll
        for (int t = 0; t < 32; ++t) {
            unsigned a = rr2 ? (pk[t] >> 16) : (pk[t] & 0xFFFFu);
            mx = umax2(mx, a);
        }
        // 2. bitonic ascending sort of lane maxima; tau16 = rank-32 (lane 32)
        {
            unsigned v = mx;
            #pragma unroll
            for (int k = 2; k <= 64; k <<= 1)
                #pragma unroll
                for (int j = k >> 1; j >= 1; j >>= 1) {
                    unsigned o = __shfl_xor(v, j);
                    bool up = ((lane & k) == 0);
                    bool keepmin = (((lane & j) == 0) == up);
                    unsigned lo = v < o ? v : o, hi = v > o ? v : o;
                    v = keepmin ? lo : hi;
                }
            mx = __shfl(v, 32);
        }
        const unsigned tau16 = mx;
        const float tauf = key2f(tau16 << 16);
        const unsigned thr16 = f2key(tauf - 0.35f) >> 16;   // margin: bf16+trunc error

        // 3. ballot-prefix compaction (ascending global index order)
        int Nc = 0;
        #pragma unroll
        for (int t = 0; t < 32; ++t) {
            unsigned a = rr2 ? (pk[t] >> 16) : (pk[t] & 0xFFFFu);
            bool c = a >= thr16;
            unsigned long long b = __ballot(c);
            if (c) {
                int p = Nc + __popcll(b & lmlt);
                if (p < 192) cand[p] = (unsigned short)(t * 64 + lane);
            }
            Nc += __popcll(b);
        }
        if (Nc > 192) Nc = 192;

        // 4. q row via wave-uniform global loads (scalar broadcast)
        const float* qrow = qw + headoff + (size_t)lrow * EH;
        float4 qv[16];
        #pragma unroll
        for (int c4 = 0; c4 < 16; ++c4) qv[c4] = *(const float4*)&qrow[c4 * 4];

        if (Nc <= 64) {
            // ---- fast path: one chunk, u32 sort + ballot tie-break ----
            bool valid = lane < Nc;
            int si = valid ? (int)cand[lane] : 0;
            const float* krow = kw + headoff + (size_t)si * EH;
            float sc = 0.f;
            #pragma unroll
            for (int c4 = 0; c4 < 16; ++c4) {      // ascending e: bit-identical
                float4 kv = *(const float4*)&krow[c4 * 4];
                sc = fmaf(qv[c4].x, kv.x, sc);
                sc = fmaf(qv[c4].y, kv.y, sc);
                sc = fmaf(qv[c4].z, kv.z, sc);
                sc = fmaf(qv[c4].w, kv.w, sc);
            }
            unsigned k32 = valid ? f2key(sc) : 0u;   // 0 < any real key
            unsigned sorted = sort32_desc(k32, lane);
            const unsigned T   = __builtin_amdgcn_readlane((int)sorted, 31);
            const unsigned M32 = __builtin_amdgcn_readlane((int)sorted, 0);
            unsigned long long bgt = __ballot(k32 > T);
            int needEq = TK - __popcll(bgt);
            unsigned long long beq = __ballot(valid && (k32 == T));
            int eqrank = __popcll(beq & lmlt);       // cand ascending-index => lowest idx first
            bool kept = valid && ((k32 > T) || ((k32 == T) && (eqrank < needEq)));
            const float M = key2f(M32);
            float ee = kept ? __expf(0.125f * (sc - M)) : 0.f;
            float Z = ee;
            #pragma unroll
            for (int d = 1; d < 64; d <<= 1) Z += __shfl_xor(Z, d);
            float w = ee / Z;
            // compact (si, w) to lanes 0..31 via ds_permute push (rank = kept prefix)
            unsigned long long bk = __ballot(kept);
            int rk = __popcll(bk & lmlt);
            int addr = kept ? (rk * 4) : 252;        // non-kept push to dead lane 63
            int psi = __builtin_amdgcn_ds_permute(addr, si);
            int pw  = __builtin_amdgcn_ds_permute(addr, __float_as_int(w));
            selS[rr2] = psi;
            selW[rr2] = __int_as_float(pw);
        } else {
            // ---- fallback: u64 composite chunked sort (rounds 5-12 proven) ----
            const int nch = (Nc + 63) >> 6;
            unsigned long long best = 0ull;
            for (int c = 0; c < nch; ++c) {
                int p = c * 64 + lane;
                bool valid = p < Nc;
                int si = valid ? (int)cand[p] : 0;
                const float* krow = kw + headoff + (size_t)si * EH;
                float sc = 0.f;
                #pragma unroll
                for (int c4 = 0; c4 < 16; ++c4) {
                    float4 kv = *(const float4*)&krow[c4 * 4];
                    sc = fmaf(qv[c4].x, kv.x, sc);
                    sc = fmaf(qv[c4].y, kv.y, sc);
                    sc = fmaf(qv[c4].z, kv.z, sc);
                    sc = fmaf(qv[c4].w, kv.w, sc);
                }
                unsigned long long comp = valid
                    ? ((((unsigned long long)f2key(sc)) << 32) | (unsigned)(~si))
                    : 0ull;
                comp = sort64_desc(comp, lane);
                best = (c == 0) ? comp : merge_top64(best, comp, lane);
            }
            unsigned key32 = (unsigned)(best >> 32);
            int si = (int)(~((unsigned)best)) & 2047;
            float sc = key2f(key32);
            float M = __shfl(sc, 0);
            float ee = (lane < TK) ? __expf(0.125f * (sc - M)) : 0.f;
            float Z = ee;
            #pragma unroll
            for (int d = 1; d < 64; d <<= 1) Z += __shfl_xor(Z, d);
            selS[rr2] = si;
            selW[rr2] = ee / Z;
        }
    }

    // ---- Epilogue: A rows staged in wave-private 8KB LDS + V rows ----
    // NT stores for A and V (write-once streams; preserve L2 for khi/k/v/q).
    float* abuf = (float*)((char*)scores16 + uwv * 8192);   // wave-private 2048 f32
    {
        float4* ab4 = (float4*)abuf;
        const float4 z4 = make_float4(0.f, 0.f, 0.f, 0.f);
        #pragma unroll
        for (int u = 0; u < 8; ++u) ab4[u * 64 + lane] = z4;   // zero ONCE per wave
    }
    #pragma unroll
    for (int rr2 = 0; rr2 < 2; ++rr2) {
        const int lrow = l0 + r0 + rr2;
        f32x4* ab4 = (f32x4*)abuf;
        if (lane < TK) abuf[selS[rr2]] = selW[rr2];          // wave-local scatter
        float* Arow = outA + ((size_t)head * 2048 + lrow) * 2048;
        #pragma unroll
        for (int u = 0; u < 8; ++u) {
            f32x4 av = ab4[u * 64 + lane];
            __builtin_nontemporal_store(av, (f32x4*)&Arow[(u * 64 + lane) * 4]);
        }
        if (lane < TK) abuf[selS[rr2]] = 0.f;                // clear only scatters

        // V: broadcast slots via readlane (VALU) -> coalesced loads
        float acc = 0.f;
        int   siv = selS[rr2];
        unsigned wbits = __float_as_uint(selW[rr2]);
        #pragma unroll
        for (int i = 0; i < TK; ++i) {
            int s_i   = __builtin_amdgcn_readlane(siv, i);
            float w_i = __uint_as_float((unsigned)__builtin_amdgcn_readlane((int)wbits, i));
            acc = fmaf(w_i, vw[headoff + (size_t)s_i * EH + lane], acc);
        }
        const int n = head >> 3, h = head & 7;
        __builtin_nontemporal_store(acc,
            &outV[((size_t)(n * 2048 + lrow)) * 512 + h * 64 + lane]);
    }
}

// ---------------------------------------------------------------------------
extern "C" void kernel_launch(void* const* d_in, const int* in_sizes, int n_in,
                              void* d_out, int out_size, void* d_ws, size_t ws_size,
                              hipStream_t stream)
{
    (void)in_sizes; (void)n_in; (void)out_size; (void)ws_size;
    const float* q  = (const float*)d_in[0];
    const float* k  = (const float*)d_in[1];
    const float* v  = (const float*)d_in[2];
    const float* Wq = (const float*)d_in[3];
    const float* bq = (const float*)d_in[4];
    const float* Wk = (const float*)d_in[5];
    const float* bk = (const float*)d_in[6];
    const float* Wv = (const float*)d_in[7];
    const float* bv = (const float*)d_in[8];
    float* ws   = (float*)d_ws;  // 28 MiB
    float* outV = (float*)d_out;
    float* outA = outV + (size_t)NBATCH * LSEQ * HD;

    proj_kernel<<<dim3(64, 4, 3), 256, 0, stream>>>(q, k, v, Wq, bq, Wk, bk, Wv, bv, ws);
    attn_kernel<<<dim3(2048, 1, 1), 512, 0, stream>>>(ws, outV, outA);
}